// Round 3
// baseline (825.084 us; speedup 1.0000x reference)
//
#include <hip/hip_runtime.h>

#define LQ 8500   // queries per (n,t1) group; also Len_in = 6400+1600+400+100 = 8500

__device__ __forceinline__ unsigned short f2h(float f) {
    return __builtin_bit_cast(unsigned short, (_Float16)f);
}
__device__ __forceinline__ float hlo(unsigned w) {
    return (float)__builtin_bit_cast(_Float16, (unsigned short)(w & 0xffffu));
}
__device__ __forceinline__ float hhi(unsigned w) {
    return (float)__builtin_bit_cast(_Float16, (unsigned short)(w >> 16));
}

// ---------------------------------------------------------------------------
// Kernel 0: concat [Woff | Watt] -> Wcat[256][384], [boff | batt] -> bcat[384]
// ---------------------------------------------------------------------------
__global__ __launch_bounds__(256) void prep_wcat(const float* __restrict__ Woff,
                                                 const float* __restrict__ boff,
                                                 const float* __restrict__ Watt,
                                                 const float* __restrict__ batt,
                                                 float* __restrict__ Wcat,
                                                 float* __restrict__ bcat) {
    int idx = blockIdx.x * 256 + threadIdx.x;
    if (idx < 256 * 384) {
        int k = idx / 384, j = idx - k * 384;
        Wcat[idx] = (j < 256) ? Woff[k * 256 + j] : Watt[k * 128 + (j - 256)];
    } else if (idx < 256 * 384 + 384) {
        int j = idx - 256 * 384;
        bcat[j] = (j < 256) ? boff[j] : batt[j - 256];
    }
}

// ---------------------------------------------------------------------------
// Kernel 1: Xs[g=n*4+t1][i][c] = sum_{t2 in [t1-1,t1+1] cap [0,4)} input[n][t2][i][c]
// ---------------------------------------------------------------------------
__global__ __launch_bounds__(256) void sum_frames(const float4* __restrict__ inp,
                                                  float4* __restrict__ Xs) {
    int g = blockIdx.y;               // n*4 + t1
    int t1 = g & 3, n = g >> 2;
    int f = blockIdx.x * 256 + threadIdx.x;
    if (f >= LQ * 64) return;
    int t2a = t1 == 0 ? 0 : t1 - 1;
    int t2b = t1 == 3 ? 3 : t1 + 1;
    float4 s = {0.f, 0.f, 0.f, 0.f};
    for (int t2 = t2a; t2 <= t2b; ++t2) {
        float4 v = inp[(size_t)(n * 4 + t2) * (LQ * 64) + f];
        s.x += v.x; s.y += v.y; s.z += v.z; s.w += v.w;
    }
    Xs[(size_t)g * (LQ * 64) + f] = s;
}

// ---------------------------------------------------------------------------
// fp32 tiled GEMM  C[R x N] = A[R x 256] @ W[256 x N] + bias*scale(row group).
// OUTMODE 0: fp32 flat. 1: fp16, Vs plane layout [(g*8+m)][pos][32] (N==256).
// 2: fp16 flat.
// ---------------------------------------------------------------------------
template <int OUTMODE>
__global__ __launch_bounds__(256) void gemm_k256(const float* __restrict__ A,
                                                 const float* __restrict__ W,
                                                 const float* __restrict__ bias,
                                                 float* __restrict__ Cf,
                                                 unsigned short* __restrict__ Ch,
                                                 int R, int N, int rows_per_group,
                                                 float s0, float s1, float s2, float s3) {
    __shared__ float As[64][33];
    __shared__ float Ws[32][64];
    int tid = threadIdx.x;
    int tx = tid & 15, ty = tid >> 4;
    int r0 = blockIdx.x * 64, c0 = blockIdx.y * 64;
    float acc[4][4] = {};

    for (int k0 = 0; k0 < 256; k0 += 32) {
#pragma unroll
        for (int li = 0; li < 2; ++li) {
            int f = li * 256 + tid;
            int row = f >> 3, c4 = (f & 7) * 4;
            float4 v = {0.f, 0.f, 0.f, 0.f};
            if (r0 + row < R)
                v = *reinterpret_cast<const float4*>(&A[(size_t)(r0 + row) * 256 + k0 + c4]);
            As[row][c4 + 0] = v.x; As[row][c4 + 1] = v.y;
            As[row][c4 + 2] = v.z; As[row][c4 + 3] = v.w;
        }
#pragma unroll
        for (int li = 0; li < 2; ++li) {
            int f = li * 256 + tid;
            int row = f >> 4, c4 = (f & 15) * 4;
            float4 v = *reinterpret_cast<const float4*>(&W[(size_t)(k0 + row) * N + c0 + c4]);
            Ws[row][c4 + 0] = v.x; Ws[row][c4 + 1] = v.y;
            Ws[row][c4 + 2] = v.z; Ws[row][c4 + 3] = v.w;
        }
        __syncthreads();
#pragma unroll 8
        for (int kk = 0; kk < 32; ++kk) {
            float a0 = As[ty * 4 + 0][kk], a1 = As[ty * 4 + 1][kk];
            float a2 = As[ty * 4 + 2][kk], a3 = As[ty * 4 + 3][kk];
            float b0 = Ws[kk][tx * 4 + 0], b1 = Ws[kk][tx * 4 + 1];
            float b2 = Ws[kk][tx * 4 + 2], b3 = Ws[kk][tx * 4 + 3];
            acc[0][0] += a0 * b0; acc[0][1] += a0 * b1; acc[0][2] += a0 * b2; acc[0][3] += a0 * b3;
            acc[1][0] += a1 * b0; acc[1][1] += a1 * b1; acc[1][2] += a1 * b2; acc[1][3] += a1 * b3;
            acc[2][0] += a2 * b0; acc[2][1] += a2 * b1; acc[2][2] += a2 * b2; acc[2][3] += a2 * b3;
            acc[3][0] += a3 * b0; acc[3][1] += a3 * b1; acc[3][2] += a3 * b2; acc[3][3] += a3 * b3;
        }
        __syncthreads();
    }

    int col = c0 + tx * 4;
    float4 bv = *reinterpret_cast<const float4*>(&bias[col]);
#pragma unroll
    for (int i = 0; i < 4; ++i) {
        int row = r0 + ty * 4 + i;
        if (row >= R) continue;
        float sc = 1.f;
        if (rows_per_group > 0) {
            int gi = (row / rows_per_group) & 3;
            sc = gi == 0 ? s0 : gi == 1 ? s1 : gi == 2 ? s2 : s3;
        }
        float o0 = acc[i][0] + bv.x * sc;
        float o1 = acc[i][1] + bv.y * sc;
        float o2 = acc[i][2] + bv.z * sc;
        float o3 = acc[i][3] + bv.w * sc;
        if (OUTMODE == 0) {
            float4 o = {o0, o1, o2, o3};
            *reinterpret_cast<float4*>(&Cf[(size_t)row * N + col]) = o;
        } else if (OUTMODE == 1) {
            // Vs plane layout: row = g*8500 + pos, col = m*32 + c
            int g = row / LQ, pos = row - g * LQ;
            int m = col >> 5, c = col & 31;
            size_t dst = ((size_t)(g * 8 + m) * LQ + pos) * 32 + c;
            ushort4 o = {f2h(o0), f2h(o1), f2h(o2), f2h(o3)};
            *reinterpret_cast<ushort4*>(&Ch[dst]) = o;
        } else {
            ushort4 o = {f2h(o0), f2h(o1), f2h(o2), f2h(o3)};
            *reinterpret_cast<ushort4*>(&Ch[(size_t)row * N + col]) = o;
        }
    }
}

// ---------------------------------------------------------------------------
// Kernel 3: LDS-free sampler. Thread = (q, m): softmax + 16 bilinear samples,
// accumulating 32 fp32 channels from fp16 Vs planes; block = 32 q of one g.
// ---------------------------------------------------------------------------
__global__ __launch_bounds__(256) void sample_kernel(const unsigned short* __restrict__ P,
                                                     const float* __restrict__ refp,
                                                     const unsigned short* __restrict__ Vs,
                                                     float* __restrict__ O) {
    int tid = threadIdx.x, bid = blockIdx.x;
    int g = bid & 7;                   // n*4 + t1  (also ~XCD id for L2 affinity)
    int q0 = (bid >> 3) * 32;
    int ql = tid >> 3, m = tid & 7;
    int q = q0 + ql;
    if (q >= LQ) return;

    const size_t qrow = (size_t)g * LQ + q;

    // ---- load off (32 fp16 -> 16 packed uints) and att (16 fp16) ----
    unsigned ow[16];
    {
        const uint4* po = reinterpret_cast<const uint4*>(P + qrow * 384 + m * 32);
        uint4 a = po[0], b = po[1], c = po[2], d = po[3];
        ow[0] = a.x; ow[1] = a.y; ow[2] = a.z; ow[3] = a.w;
        ow[4] = b.x; ow[5] = b.y; ow[6] = b.z; ow[7] = b.w;
        ow[8] = c.x; ow[9] = c.y; ow[10] = c.z; ow[11] = c.w;
        ow[12] = d.x; ow[13] = d.y; ow[14] = d.z; ow[15] = d.w;
    }
    float wgt[16];
    {
        const uint4* pa = reinterpret_cast<const uint4*>(P + qrow * 384 + 256 + m * 16);
        uint4 a = pa[0], b = pa[1];
        unsigned aw[8] = {a.x, a.y, a.z, a.w, b.x, b.y, b.z, b.w};
#pragma unroll
        for (int j = 0; j < 8; ++j) {
            wgt[j * 2 + 0] = hlo(aw[j]);
            wgt[j * 2 + 1] = hhi(aw[j]);
        }
        float mx = -1e30f;
#pragma unroll
        for (int j = 0; j < 16; ++j) mx = fmaxf(mx, wgt[j]);
        float s = 0.f;
#pragma unroll
        for (int j = 0; j < 16; ++j) { wgt[j] = __expf(wgt[j] - mx); s += wgt[j]; }
        int t1 = g & 3;
        float Kc = (t1 == 0 || t1 == 3) ? 2.f : 3.f;
        float inv = 1.f / (s * Kc);
#pragma unroll
        for (int j = 0; j < 16; ++j) wgt[j] *= inv;
    }

    // ---- reference points ----
    float rx[4], ry[4];
    {
        const float4* rp = reinterpret_cast<const float4*>(refp + qrow * 8);
        float4 r0 = rp[0], r1 = rp[1];
        rx[0] = r0.x; ry[0] = r0.y; rx[1] = r0.z; ry[1] = r0.w;
        rx[2] = r1.x; ry[2] = r1.y; rx[3] = r1.z; ry[3] = r1.w;
    }

    float acc[32];
#pragma unroll
    for (int d = 0; d < 32; ++d) acc[d] = 0.f;

    const unsigned short* vplane = Vs + (size_t)(g * 8 + m) * (LQ * 32);

#pragma unroll
    for (int p = 0; p < 16; ++p) {
        const int l = p >> 2;
        const int Wl = 80 >> l;
        const int start = (l == 0) ? 0 : (l == 1) ? 6400 : (l == 2) ? 8000 : 8400;
        const float Wlf = (float)Wl;

        float x = fmaf(rx[l], Wlf, hlo(ow[p])) - 0.5f;
        float y = fmaf(ry[l], Wlf, hhi(ow[p])) - 0.5f;
        float w = wgt[p];

        float xf = floorf(x), yf = floorf(y);
        int x0 = (int)xf, y0 = (int)yf;
        float wx1 = x - xf, wy1 = y - yf;

        int xb = min(max(x0, 0), Wl - 2);
        float wl = (x0 == xb) ? 1.f - wx1 : ((x0 + 1 == xb) ? wx1 : 0.f);
        float wr = (x0 == xb) ? wx1 : ((x0 - 1 == xb) ? 1.f - wx1 : 0.f);

        int yc[2];
        float cw[2];
        yc[0] = min(max(y0, 0), Wl - 1);
        cw[0] = (y0 >= 0 && y0 < Wl) ? (1.f - wy1) * w : 0.f;
        int y1i = y0 + 1;
        yc[1] = min(max(y1i, 0), Wl - 1);
        cw[1] = (y1i >= 0 && y1i < Wl) ? wy1 * w : 0.f;

#pragma unroll
        for (int ryi = 0; ryi < 2; ++ryi) {
            float cl = cw[ryi] * wl, cr = cw[ryi] * wr;
            const uint4* v4 = reinterpret_cast<const uint4*>(
                vplane + (size_t)(start + yc[ryi] * Wl + xb) * 32);
#pragma unroll
            for (int k = 0; k < 4; ++k) {
                uint4 a = v4[k];       // left column, channels k*8..k*8+7
                acc[k * 8 + 0] += cl * hlo(a.x); acc[k * 8 + 1] += cl * hhi(a.x);
                acc[k * 8 + 2] += cl * hlo(a.y); acc[k * 8 + 3] += cl * hhi(a.y);
                acc[k * 8 + 4] += cl * hlo(a.z); acc[k * 8 + 5] += cl * hhi(a.z);
                acc[k * 8 + 6] += cl * hlo(a.w); acc[k * 8 + 7] += cl * hhi(a.w);
            }
#pragma unroll
            for (int k = 0; k < 4; ++k) {
                uint4 b = v4[4 + k];   // right column (x+1)
                acc[k * 8 + 0] += cr * hlo(b.x); acc[k * 8 + 1] += cr * hhi(b.x);
                acc[k * 8 + 2] += cr * hlo(b.y); acc[k * 8 + 3] += cr * hhi(b.y);
                acc[k * 8 + 4] += cr * hlo(b.z); acc[k * 8 + 5] += cr * hhi(b.z);
                acc[k * 8 + 6] += cr * hlo(b.w); acc[k * 8 + 7] += cr * hhi(b.w);
            }
        }
    }

    float* op = O + qrow * 256 + m * 32;
#pragma unroll
    for (int k = 0; k < 8; ++k) {
        float4 o = {acc[k * 4 + 0], acc[k * 4 + 1], acc[k * 4 + 2], acc[k * 4 + 3]};
        reinterpret_cast<float4*>(op)[k] = o;
    }
}

// ---------------------------------------------------------------------------
extern "C" void kernel_launch(void* const* d_in, const int* in_sizes, int n_in,
                              void* d_out, int out_size, void* d_ws, size_t ws_size,
                              hipStream_t stream) {
    const float* query = (const float*)d_in[0];
    const float* refp  = (const float*)d_in[1];
    const float* inp   = (const float*)d_in[2];
    const float* Woff = (const float*)d_in[5];
    const float* boff = (const float*)d_in[6];
    const float* Watt = (const float*)d_in[7];
    const float* batt = (const float*)d_in[8];
    const float* Wval = (const float*)d_in[9];
    const float* bval = (const float*)d_in[10];
    const float* Wout = (const float*)d_in[11];
    const float* bout = (const float*)d_in[12];
    float* out = (float*)d_out;

    // workspace layout (bytes):
    //   Xs  fp32 [68000][256]           @ 0          (69,632,000)  -- later reused as O
    //   Vs  fp16 [8g][8m][8500][32]     @ 69,632,000 (34,816,000)
    //   P   fp16 [68000][384]           @ 104,448,000 (52,224,000)
    //   Wcat fp32 [256][384], bcat[384] @ 156,672,000 (394,752)
    char* base = (char*)d_ws;
    float* Xs = (float*)base;
    unsigned short* Vs = (unsigned short*)(base + 69632000);
    unsigned short* P  = (unsigned short*)(base + 104448000);
    float* Wcat = (float*)(base + 156672000);
    float* bcat = Wcat + 256 * 384;
    float* O = Xs;  // alias: Xs dead after value GEMM

    // 0) weight concat
    prep_wcat<<<dim3((256 * 384 + 384 + 255) / 256), 256, 0, stream>>>(
        Woff, boff, Watt, batt, Wcat, bcat);

    // 1) per-t1 frame sums (g = n*4+t1)
    sum_frames<<<dim3((LQ * 64 + 255) / 256, 8), 256, 0, stream>>>(
        (const float4*)inp, (float4*)Xs);

    // 2) Vs = fp16( Xs @ W_val + K(t1)*b_val ), plane layout
    gemm_k256<1><<<dim3((8 * LQ + 63) / 64, 4), 256, 0, stream>>>(
        Xs, Wval, bval, nullptr, Vs, 8 * LQ, 256, LQ, 2.f, 3.f, 3.f, 2.f);

    // 3) P = fp16( query @ Wcat + bcat )
    gemm_k256<2><<<dim3((8 * LQ + 63) / 64, 6), 256, 0, stream>>>(
        query, Wcat, bcat, nullptr, P, 8 * LQ, 384, 0, 1.f, 1.f, 1.f, 1.f);

    // 4) sampler -> O (aliases Xs)
    sample_kernel<<<dim3(((LQ + 31) / 32) * 8), 256, 0, stream>>>(
        P, refp, Vs, O);

    // 5) d_out = O @ W_out + b_out
    gemm_k256<0><<<dim3((8 * LQ + 63) / 64, 4), 256, 0, stream>>>(
        O, Wout, bout, out, nullptr, 8 * LQ, 256, 0, 1.f, 1.f, 1.f, 1.f);
}

// Round 4
// 337.875 us; speedup vs baseline: 2.4420x; 2.4420x over previous
//
#include <hip/hip_runtime.h>

#define LQ 8500

typedef _Float16 half8 __attribute__((ext_vector_type(8)));
typedef float f32x4 __attribute__((ext_vector_type(4)));

__device__ __forceinline__ unsigned short f2h(float f) {
    return __builtin_bit_cast(unsigned short, (_Float16)f);
}
__device__ __forceinline__ float hlo(unsigned w) {
    return (float)__builtin_bit_cast(_Float16, (unsigned short)(w & 0xffffu));
}
__device__ __forceinline__ float hhi(unsigned w) {
    return (float)__builtin_bit_cast(_Float16, (unsigned short)(w >> 16));
}
__device__ __forceinline__ unsigned pk2(float a, float b) {
    return (unsigned)f2h(a) | ((unsigned)f2h(b) << 16);
}

// ---------------------------------------------------------------------------
// Kernel 0: weight prep. Wct[384][256] = [Woff|Watt]^T fp16, Wvt = Wval^T fp16,
// Wot = Wout^T fp16, bcat[384] fp32.
// ---------------------------------------------------------------------------
__global__ __launch_bounds__(256) void prep_weights(const float* __restrict__ Woff,
                                                    const float* __restrict__ boff,
                                                    const float* __restrict__ Watt,
                                                    const float* __restrict__ batt,
                                                    const float* __restrict__ Wval,
                                                    const float* __restrict__ Wout,
                                                    unsigned short* __restrict__ Wct,
                                                    unsigned short* __restrict__ Wvt,
                                                    unsigned short* __restrict__ Wot,
                                                    float* __restrict__ bcat) {
    int idx = blockIdx.x * 256 + threadIdx.x;
    if (idx < 98304) {                       // Wct[j][k] = Wcat[k][j]
        int j = idx >> 8, k = idx & 255;
        float v = (j < 256) ? Woff[k * 256 + j] : Watt[k * 128 + (j - 256)];
        Wct[idx] = f2h(v);
    } else if (idx < 98304 + 65536) {        // Wvt[n][k] = Wval[k][n]
        int t = idx - 98304;
        int n = t >> 8, k = t & 255;
        Wvt[t] = f2h(Wval[k * 256 + n]);
    } else if (idx < 98304 + 131072) {       // Wot[n][k] = Wout[k][n]
        int t = idx - 98304 - 65536;
        int n = t >> 8, k = t & 255;
        Wot[t] = f2h(Wout[k * 256 + n]);
    } else if (idx < 98304 + 131072 + 384) {
        int j = idx - 98304 - 131072;
        bcat[j] = (j < 256) ? boff[j] : batt[j - 256];
    }
}

// ---------------------------------------------------------------------------
// Kernel 1: fp32 -> fp16 convert (8 elems / thread)
// ---------------------------------------------------------------------------
__global__ __launch_bounds__(256) void conv_f32_f16(const float4* __restrict__ in,
                                                    uint4* __restrict__ out, int n8) {
    int i = blockIdx.x * 256 + threadIdx.x;
    if (i >= n8) return;
    float4 a = in[2 * i], b = in[2 * i + 1];
    uint4 o;
    o.x = pk2(a.x, a.y); o.y = pk2(a.z, a.w);
    o.z = pk2(b.x, b.y); o.w = pk2(b.z, b.w);
    out[i] = o;
}

// ---------------------------------------------------------------------------
// Kernel 2: frame sums -> fp16 Xs. 8 channels/thread.
// ---------------------------------------------------------------------------
__global__ __launch_bounds__(256) void sum_frames(const float4* __restrict__ inp,
                                                  uint4* __restrict__ Xs) {
    int g = blockIdx.y;               // n*4 + t1
    int t1 = g & 3, n = g >> 2;
    int f = blockIdx.x * 256 + threadIdx.x;      // 8-elem chunk index
    if (f >= LQ * 32) return;
    int t2a = t1 == 0 ? 0 : t1 - 1;
    int t2b = t1 == 3 ? 3 : t1 + 1;
    float4 s0 = {0, 0, 0, 0}, s1 = {0, 0, 0, 0};
    for (int t2 = t2a; t2 <= t2b; ++t2) {
        const float4* p = inp + (size_t)(n * 4 + t2) * (LQ * 64) + (size_t)f * 2;
        float4 a = p[0], b = p[1];
        s0.x += a.x; s0.y += a.y; s0.z += a.z; s0.w += a.w;
        s1.x += b.x; s1.y += b.y; s1.z += b.z; s1.w += b.w;
    }
    uint4 o;
    o.x = pk2(s0.x, s0.y); o.y = pk2(s0.z, s0.w);
    o.z = pk2(s1.x, s1.y); o.w = pk2(s1.z, s1.w);
    Xs[(size_t)g * (LQ * 32) + f] = o;
}

// ---------------------------------------------------------------------------
// MFMA fp16 GEMM: C[M x N] = A[M x 256] @ Bt[N x 256]^T + bias.
// 128x128 tile, BK=32, 256 threads = 4 waves (2x2, each 64x64 = 4x4 frags).
// OUTMODE 0: fp32 flat N=256 (+bias). 1: fp16 Vs-plane N=256 (+bias*K(t1)).
// 2: fp16 flat N=384 (+bias).
// ---------------------------------------------------------------------------
template <int OUTMODE>
__global__ __launch_bounds__(256) void gemm_f16(const unsigned short* __restrict__ A,
                                                const unsigned short* __restrict__ Bt,
                                                const float* __restrict__ bias,
                                                void* __restrict__ Cout, int M) {
    __shared__ char lds[16384];       // As 8KB @0, Bs 8KB @8192 (both [128][32] f16, swizzled)
    const int tid = threadIdx.x;
    const int r0 = blockIdx.x * 128, c0 = blockIdx.y * 128;
    const int wid = tid >> 6, lane = tid & 63;
    const int wr = (wid >> 1) * 64, wc = (wid & 1) * 64;

    f32x4 acc[4][4] = {};

    for (int k0 = 0; k0 < 256; k0 += 32) {
#pragma unroll
        for (int cc = 0; cc < 2; ++cc) {
            int ch = cc * 256 + tid;           // 0..511 chunk of 16B
            int row = ch >> 2, seg = ch & 3;
            int byte = (row << 6) + (seg << 4);
            int swz = byte ^ ((row & 7) << 4);
            uint4 va = {0, 0, 0, 0};
            int ar = r0 + row;
            if (ar < M)
                va = *reinterpret_cast<const uint4*>(A + (size_t)ar * 256 + k0 + seg * 8);
            *reinterpret_cast<uint4*>(lds + swz) = va;
            uint4 vb = *reinterpret_cast<const uint4*>(Bt + (size_t)(c0 + row) * 256 + k0 + seg * 8);
            *reinterpret_cast<uint4*>(lds + 8192 + swz) = vb;
        }
        __syncthreads();
        half8 af[4], bf[4];
#pragma unroll
        for (int i = 0; i < 4; ++i) {
            int rowA = wr + i * 16 + (lane & 15);
            int byteA = (rowA << 6) + ((lane >> 4) << 4);
            af[i] = *reinterpret_cast<const half8*>(lds + (byteA ^ ((rowA & 7) << 4)));
            int rowB = wc + i * 16 + (lane & 15);
            int byteB = (rowB << 6) + ((lane >> 4) << 4);
            bf[i] = *reinterpret_cast<const half8*>(lds + 8192 + (byteB ^ ((rowB & 7) << 4)));
        }
#pragma unroll
        for (int i = 0; i < 4; ++i)
#pragma unroll
            for (int j = 0; j < 4; ++j)
                acc[i][j] = __builtin_amdgcn_mfma_f32_16x16x32_f16(af[i], bf[j], acc[i][j], 0, 0, 0);
        __syncthreads();
    }

#pragma unroll
    for (int j = 0; j < 4; ++j) {
        int col = c0 + wc + j * 16 + (lane & 15);
        float bv = bias[col];
#pragma unroll
        for (int i = 0; i < 4; ++i) {
#pragma unroll
            for (int r = 0; r < 4; ++r) {
                int row = r0 + wr + i * 16 + (lane >> 4) * 4 + r;
                if (row >= M) continue;
                float v = acc[i][j][r];
                if (OUTMODE == 1) {
                    int g = row / LQ;
                    int pos = row - g * LQ;
                    int t1 = g & 3;
                    float sc = (t1 == 0 || t1 == 3) ? 2.f : 3.f;
                    v += bv * sc;
                    int m = col >> 5, c = col & 31;
                    ((unsigned short*)Cout)[((size_t)(g * 8 + m) * LQ + pos) * 32 + c] = f2h(v);
                } else if (OUTMODE == 2) {
                    ((unsigned short*)Cout)[(size_t)row * 384 + col] = f2h(v + bv);
                } else {
                    ((float*)Cout)[(size_t)row * 256 + col] = v + bv;
                }
            }
        }
    }
}

// ---------------------------------------------------------------------------
// Kernel 4: LDS-free sampler. Thread = (q, m, half): 16 fp32 channels.
// Block = 16 q x 8 m x 2 half of one group g (bid & 7 -> XCD/L2 affinity).
// ---------------------------------------------------------------------------
__global__ __launch_bounds__(256) void sample_kernel(const unsigned short* __restrict__ P,
                                                     const float* __restrict__ refp,
                                                     const unsigned short* __restrict__ Vs,
                                                     unsigned short* __restrict__ O16) {
    int tid = threadIdx.x, bid = blockIdx.x;
    int g = bid & 7;
    int q0 = (bid >> 3) * 16;
    int ql = tid >> 4, m = (tid >> 1) & 7, h = tid & 1;
    int q = q0 + ql;
    if (q >= LQ) return;

    const size_t qrow = (size_t)g * LQ + q;

    // offsets (32 fp16) + att logits (16 fp16)
    unsigned ow[16];
    {
        const uint4* po = reinterpret_cast<const uint4*>(P + qrow * 384 + m * 32);
        uint4 a = po[0], b = po[1], c = po[2], d = po[3];
        ow[0] = a.x; ow[1] = a.y; ow[2] = a.z; ow[3] = a.w;
        ow[4] = b.x; ow[5] = b.y; ow[6] = b.z; ow[7] = b.w;
        ow[8] = c.x; ow[9] = c.y; ow[10] = c.z; ow[11] = c.w;
        ow[12] = d.x; ow[13] = d.y; ow[14] = d.z; ow[15] = d.w;
    }
    float wgt[16];
    {
        const uint4* pa = reinterpret_cast<const uint4*>(P + qrow * 384 + 256 + m * 16);
        uint4 a = pa[0], b = pa[1];
        unsigned aw[8] = {a.x, a.y, a.z, a.w, b.x, b.y, b.z, b.w};
#pragma unroll
        for (int j = 0; j < 8; ++j) {
            wgt[j * 2 + 0] = hlo(aw[j]);
            wgt[j * 2 + 1] = hhi(aw[j]);
        }
        float mx = -1e30f;
#pragma unroll
        for (int j = 0; j < 16; ++j) mx = fmaxf(mx, wgt[j]);
        float s = 0.f;
#pragma unroll
        for (int j = 0; j < 16; ++j) { wgt[j] = __expf(wgt[j] - mx); s += wgt[j]; }
        int t1 = g & 3;
        float Kc = (t1 == 0 || t1 == 3) ? 2.f : 3.f;
        float inv = 1.f / (s * Kc);
#pragma unroll
        for (int j = 0; j < 16; ++j) wgt[j] *= inv;
    }

    float rx[4], ry[4];
    {
        const float4* rp = reinterpret_cast<const float4*>(refp + qrow * 8);
        float4 r0 = rp[0], r1 = rp[1];
        rx[0] = r0.x; ry[0] = r0.y; rx[1] = r0.z; ry[1] = r0.w;
        rx[2] = r1.x; ry[2] = r1.y; rx[3] = r1.z; ry[3] = r1.w;
    }

    float acc[16];
#pragma unroll
    for (int d = 0; d < 16; ++d) acc[d] = 0.f;

    const unsigned short* vplane = Vs + (size_t)(g * 8 + m) * (LQ * 32) + h * 16;

#pragma unroll
    for (int p = 0; p < 16; ++p) {
        const int l = p >> 2;
        const int Wl = 80 >> l;
        const int start = (l == 0) ? 0 : (l == 1) ? 6400 : (l == 2) ? 8000 : 8400;
        const float Wlf = (float)Wl;

        float x = fmaf(rx[l], Wlf, hlo(ow[p])) - 0.5f;
        float y = fmaf(ry[l], Wlf, hhi(ow[p])) - 0.5f;
        float w = wgt[p];

        float xf = floorf(x), yf = floorf(y);
        int x0 = (int)xf, y0 = (int)yf;
        float wx1 = x - xf, wy1 = y - yf;

        int xb = min(max(x0, 0), Wl - 2);
        float wl = (x0 == xb) ? 1.f - wx1 : ((x0 + 1 == xb) ? wx1 : 0.f);
        float wr = (x0 == xb) ? wx1 : ((x0 - 1 == xb) ? 1.f - wx1 : 0.f);

        int yc[2];
        float cw[2];
        yc[0] = min(max(y0, 0), Wl - 1);
        cw[0] = (y0 >= 0 && y0 < Wl) ? (1.f - wy1) * w : 0.f;
        int y1i = y0 + 1;
        yc[1] = min(max(y1i, 0), Wl - 1);
        cw[1] = (y1i >= 0 && y1i < Wl) ? wy1 * w : 0.f;

#pragma unroll
        for (int ryi = 0; ryi < 2; ++ryi) {
            float cl = cw[ryi] * wl, cr = cw[ryi] * wr;
            const uint4* vp = reinterpret_cast<const uint4*>(
                vplane + (size_t)(start + yc[ryi] * Wl + xb) * 32);
            uint4 La = vp[0], Lb = vp[1];   // left pos, this half's 16 ch
            uint4 Ra = vp[4], Rb = vp[5];   // right pos (+32 ushort)
            acc[0]  += cl * hlo(La.x) + cr * hlo(Ra.x);
            acc[1]  += cl * hhi(La.x) + cr * hhi(Ra.x);
            acc[2]  += cl * hlo(La.y) + cr * hlo(Ra.y);
            acc[3]  += cl * hhi(La.y) + cr * hhi(Ra.y);
            acc[4]  += cl * hlo(La.z) + cr * hlo(Ra.z);
            acc[5]  += cl * hhi(La.z) + cr * hhi(Ra.z);
            acc[6]  += cl * hlo(La.w) + cr * hlo(Ra.w);
            acc[7]  += cl * hhi(La.w) + cr * hhi(Ra.w);
            acc[8]  += cl * hlo(Lb.x) + cr * hlo(Rb.x);
            acc[9]  += cl * hhi(Lb.x) + cr * hhi(Rb.x);
            acc[10] += cl * hlo(Lb.y) + cr * hlo(Rb.y);
            acc[11] += cl * hhi(Lb.y) + cr * hhi(Rb.y);
            acc[12] += cl * hlo(Lb.z) + cr * hlo(Rb.z);
            acc[13] += cl * hhi(Lb.z) + cr * hhi(Rb.z);
            acc[14] += cl * hlo(Lb.w) + cr * hlo(Rb.w);
            acc[15] += cl * hhi(Lb.w) + cr * hhi(Rb.w);
        }
    }

    unsigned short* op = O16 + qrow * 256 + m * 32 + h * 16;
    uint4 o0, o1;
    o0.x = pk2(acc[0], acc[1]);   o0.y = pk2(acc[2], acc[3]);
    o0.z = pk2(acc[4], acc[5]);   o0.w = pk2(acc[6], acc[7]);
    o1.x = pk2(acc[8], acc[9]);   o1.y = pk2(acc[10], acc[11]);
    o1.z = pk2(acc[12], acc[13]); o1.w = pk2(acc[14], acc[15]);
    reinterpret_cast<uint4*>(op)[0] = o0;
    reinterpret_cast<uint4*>(op)[1] = o1;
}

// ---------------------------------------------------------------------------
extern "C" void kernel_launch(void* const* d_in, const int* in_sizes, int n_in,
                              void* d_out, int out_size, void* d_ws, size_t ws_size,
                              hipStream_t stream) {
    const float* query = (const float*)d_in[0];
    const float* refp  = (const float*)d_in[1];
    const float* inp   = (const float*)d_in[2];
    const float* Woff = (const float*)d_in[5];
    const float* boff = (const float*)d_in[6];
    const float* Watt = (const float*)d_in[7];
    const float* batt = (const float*)d_in[8];
    const float* Wval = (const float*)d_in[9];
    const float* bval = (const float*)d_in[10];
    const float* Wout = (const float*)d_in[11];
    const float* bout = (const float*)d_in[12];
    float* out = (float*)d_out;

    // workspace layout (bytes):
    //   Xs16 f16 [68000][256]        @ 0            (34,816,000)  -- later O16 alias
    //   Vs   f16 [64 planes][8500][32] @ 34,816,000 (34,816,000)
    //   P    f16 [68000][384]        @ 69,632,000   (52,224,000)
    //   Wct  f16 [384][256]          @ 121,856,000  (196,608)
    //   Wvt  f16 [256][256]          @ 122,052,608  (131,072)
    //   Wot  f16 [256][256]          @ 122,183,680  (131,072)
    //   bcat f32 [384]               @ 122,314,752  (1,536)
    char* base = (char*)d_ws;
    unsigned short* Xs16 = (unsigned short*)base;
    unsigned short* Vs   = (unsigned short*)(base + 34816000);
    unsigned short* P    = (unsigned short*)(base + 69632000);
    unsigned short* Wct  = (unsigned short*)(base + 121856000);
    unsigned short* Wvt  = (unsigned short*)(base + 122052608);
    unsigned short* Wot  = (unsigned short*)(base + 122183680);
    float* bcat          = (float*)(base + 122314752);
    unsigned short* O16  = Xs16;                 // alias after value GEMM
    unsigned short* q16  = (unsigned short*)d_out;  // 34.8MB scratch in 69.6MB d_out

    // 0) weight prep (229,760 work items)
    prep_weights<<<dim3(898), 256, 0, stream>>>(Woff, boff, Watt, batt, Wval, Wout,
                                                Wct, Wvt, Wot, bcat);

    // 1) q16 = fp16(query): 17,408,000 elems / 8
    conv_f32_f16<<<dim3(8500), 256, 0, stream>>>((const float4*)query, (uint4*)q16,
                                                 17408000 / 8);

    // 2) Xs16 = fp16 frame sums
    sum_frames<<<dim3((LQ * 32 + 255) / 256, 8), 256, 0, stream>>>(
        (const float4*)inp, (uint4*)Xs16);

    // 3) Vs = f16( Xs16 @ Wval + K(t1)*bval ), plane layout
    gemm_f16<1><<<dim3((8 * LQ + 127) / 128, 2), 256, 0, stream>>>(
        Xs16, Wvt, bval, Vs, 8 * LQ);

    // 4) P = f16( q16 @ Wcat + bcat )
    gemm_f16<2><<<dim3((8 * LQ + 127) / 128, 3), 256, 0, stream>>>(
        q16, Wct, bcat, P, 8 * LQ);

    // 5) sampler -> O16 (aliases Xs16)
    sample_kernel<<<dim3(((LQ + 15) / 16) * 8), 256, 0, stream>>>(P, refp, Vs, O16);

    // 6) d_out = O16 @ Wout + bout (fp32)
    gemm_f16<0><<<dim3((8 * LQ + 127) / 128, 2), 256, 0, stream>>>(
        O16, Wot, bout, out, 8 * LQ);
}